// Round 14
// baseline (230.308 us; speedup 1.0000x reference)
//
#include <hip/hip_runtime.h>

#define NSTATE 18
#define NBATCH 32
#define TSTEPS 32768
#define BURN   160    // qs-init decay: B=136->5.0, B=176->2.0 measured; 160 -> 3.0 (measured R13)

// split-path geometry (R8-proven optimum)
#define RSEGS   128
#define RSEGLEN 256
// fused-fallback geometry (iv-init -> needs more burn)
#define FBURN   176
#define FSEGS   64
#define FSEGLEN 512

typedef float v2f __attribute__((ext_vector_type(2)));

// native single-instruction exp2 (v_exp_f32, <=1 ULP) — R5's win.
#define EXP2F(x) __builtin_amdgcn_exp2f(x)

// packed fp32 FMA with op_sel broadcast of src1 (X) halves.
#define PKFMA_LO(ACC, Gp, Xp) \
  asm("v_pk_fma_f32 %0, %1, %2, %0 op_sel:[0,0,0] op_sel_hi:[1,0,1]" \
      : "+v"(ACC) : "v"(Gp), "v"(Xp))
#define PKFMA_HI(ACC, Gp, Xp) \
  asm("v_pk_fma_f32 %0, %1, %2, %0 op_sel:[0,1,0] op_sel_hi:[1,1,1]" \
      : "+v"(ACC) : "v"(Gp), "v"(Xp))

// butterfly-sum level: mov_dpp + add, compiler-scheduled.
template <int CTRL>
__device__ __forceinline__ float dpp_xadd(float x) {
  int y = __builtin_amdgcn_update_dpp(0, __float_as_int(x), CTRL, 0xF, 0xF, true);
  return x + __int_as_float(y);
}

// policy evaluation chain: vlo -> (aj0, aj1).
#define POLICY(VLO, AJ0, AJ1)                                                     \
    float e2_ = EXP2F(VLO);                                                       \
    float rc_ = __builtin_amdgcn_rcpf(1.0f + e2_);                                \
    float pA_ = fmaf(nw2A, rc_, w2A);                                             \
    pA_ = dpp_xadd<0xB1>(pA_); pA_ = dpp_xadd<0x4E>(pA_);                         \
    pA_ = dpp_xadd<0x141>(pA_); pA_ = dpp_xadd<0x140>(pA_);                       \
    float ez_ = EXP2F(fmaf(pA_, -1.44269504f, nb2));                              \
    float an_ = __builtin_amdgcn_rcpf(1.0f + ez_);                                \
    AJ0 = __int_as_float(__builtin_amdgcn_readlane(__float_as_int(an_), 32));     \
    float qB_ = fmaf(AJ0, uB, VLO);                                               \
    float e2b_ = EXP2F(qB_);                                                      \
    float rcb_ = __builtin_amdgcn_rcpf(1.0f + e2b_);                              \
    float pB_ = fmaf(nw2B, rcb_, w2B);                                            \
    pB_ = dpp_xadd<0xB1>(pB_); pB_ = dpp_xadd<0x4E>(pB_);                         \
    pB_ = dpp_xadd<0x141>(pB_); pB_ = dpp_xadd<0x140>(pB_);                       \
    float ezb_ = EXP2F(fmaf(pB_, -1.44269504f, nb2));                             \
    float anb_ = __builtin_amdgcn_rcpf(1.0f + ezb_);                              \
    AJ1 = __int_as_float(__builtin_amdgcn_readlane(__float_as_int(anb_), 48))

// wave-uniform wrap correction (R8-proven).
#define TWRAP(P)                                                                  \
  do {                                                                            \
    if ((P) + 1 == pD) CBase -= dayCorr;                                          \
    if ((P) + 1 == pW) CBase -= weekCorr;                                         \
  } while (0)

// ---------------------------------------------------------------------------
// FUSED DOUBLE-STEP PAIR (steps P and P+1): numerically identical to
// STEPP(XI->XM,P) ; TWRAP(P) ; STEPP(XM->XI,P+1) ; TWRAP(P+1), but with
// policy-A's dependency chain textually INTERLEAVED with matvec-B's 18
// pk_fmas (they share no data: matvec-B needs only XM; only the final
// +clo merge needs aj0A/aj1A). R9/R13 evidence says the scheduler does not
// hoist across the long macro regions on its own; this forces the overlap.
// ---------------------------------------------------------------------------
#define STEPPAIR(XI, XM, TIN, TNX, P, DOSTORE)                                    \
  do {                                                                            \
    TNX = *(const v2f*)(ldsT + 2 * (P) + 2);                                      \
    v2f aA; aA.x = 0.0f; aA.y = 0.0f;                                             \
    v2f aB; aB.x = 0.0f; aB.y = 0.0f;                                             \
    PKFMA_LO(aA, G[0],  XI[0]);  PKFMA_HI(aB, G[1],  XI[0]);                      \
    PKFMA_LO(aA, G[2],  XI[1]);  PKFMA_HI(aB, G[3],  XI[1]);                      \
    PKFMA_LO(aA, G[4],  XI[2]);  PKFMA_HI(aB, G[5],  XI[2]);                      \
    PKFMA_LO(aA, G[6],  XI[3]);  PKFMA_HI(aB, G[7],  XI[3]);                      \
    PKFMA_LO(aA, G[8],  XI[4]);  PKFMA_HI(aB, G[9],  XI[4]);                      \
    PKFMA_LO(aA, G[10], XI[5]);  PKFMA_HI(aB, G[11], XI[5]);                      \
    PKFMA_LO(aA, G[12], XI[6]);  PKFMA_HI(aB, G[13], XI[6]);                      \
    PKFMA_LO(aA, G[14], XI[7]);  PKFMA_HI(aB, G[15], XI[7]);                      \
    PKFMA_LO(aA, G[16], XI[8]);  PKFMA_HI(aB, G[17], XI[8]);                      \
    float tbA = fmaf((float)(P), dtw, CBase);                                     \
    float cloA = fmaf(TIN.x, C0.x, fmaf(TIN.y, C1.x, tbA));                       \
    cloA = fmaf(TNX.x, C2lo, cloA);                                               \
    cloA = fmaf(a0p, F0.x, cloA);                                                 \
    cloA = fmaf(a1p, F1.x, cloA);                                                 \
    float chiA = fmaf(TIN.x, C0.y, TIN.y * C1.y);                                 \
    chiA = fmaf(a0p, F0.y, chiA);                                                 \
    chiA = fmaf(a1p, F1.y, chiA);                                                 \
    v2f mA = aA + aB;                                                             \
    float vloA = mA.x + cloA, vhiA = mA.y + chiA;                                 \
    xbuf[wIdx] = vloA; /* in-order DS per wave: lands before the reads */         \
    XM[0] = *(const v2f*)(xbuf + 0);  XM[1] = *(const v2f*)(xbuf + 2);            \
    XM[2] = *(const v2f*)(xbuf + 4);  XM[3] = *(const v2f*)(xbuf + 6);            \
    XM[4] = *(const v2f*)(xbuf + 8);  XM[5] = *(const v2f*)(xbuf + 10);           \
    XM[6] = *(const v2f*)(xbuf + 12); XM[7] = *(const v2f*)(xbuf + 14);           \
    XM[8] = *(const v2f*)(xbuf + 16);                                             \
    TIN = *(const v2f*)(ldsT + 2 * (P) + 4); /* step-B t2 + next pair's TIN */    \
    /* ---- interleave: policy-A chain || matvec-B on XM ---- */                  \
    v2f bA; bA.x = 0.0f; bA.y = 0.0f;                                             \
    v2f bB; bB.x = 0.0f; bB.y = 0.0f;                                             \
    float e2A = EXP2F(vloA);                                                      \
    PKFMA_LO(bA, G[0],  XM[0]);  PKFMA_HI(bB, G[1],  XM[0]);                      \
    float rcA = __builtin_amdgcn_rcpf(1.0f + e2A);                                \
    PKFMA_LO(bA, G[2],  XM[1]);  PKFMA_HI(bB, G[3],  XM[1]);                      \
    float pAa = fmaf(nw2A, rcA, w2A);                                             \
    PKFMA_LO(bA, G[4],  XM[2]);  PKFMA_HI(bB, G[5],  XM[2]);                      \
    pAa = dpp_xadd<0xB1>(pAa);                                                    \
    PKFMA_LO(bA, G[6],  XM[3]);  PKFMA_HI(bB, G[7],  XM[3]);                      \
    pAa = dpp_xadd<0x4E>(pAa);                                                    \
    PKFMA_LO(bA, G[8],  XM[4]);  PKFMA_HI(bB, G[9],  XM[4]);                      \
    pAa = dpp_xadd<0x141>(pAa);                                                   \
    PKFMA_LO(bA, G[10], XM[5]);  PKFMA_HI(bB, G[11], XM[5]);                      \
    pAa = dpp_xadd<0x140>(pAa);                                                   \
    PKFMA_LO(bA, G[12], XM[6]);  PKFMA_HI(bB, G[13], XM[6]);                      \
    float ezA = EXP2F(fmaf(pAa, -1.44269504f, nb2));                              \
    PKFMA_LO(bA, G[14], XM[7]);  PKFMA_HI(bB, G[15], XM[7]);                      \
    float anA = __builtin_amdgcn_rcpf(1.0f + ezA);                                \
    PKFMA_LO(bA, G[16], XM[8]);  PKFMA_HI(bB, G[17], XM[8]);                      \
    float aj0A = __int_as_float(__builtin_amdgcn_readlane(__float_as_int(anA), 32)); \
    float qBA = fmaf(aj0A, uB, vloA);                                             \
    float e2bA = EXP2F(qBA);                                                      \
    float rcbA = __builtin_amdgcn_rcpf(1.0f + e2bA);                              \
    float pBa = fmaf(nw2B, rcbA, w2B);                                            \
    pBa = dpp_xadd<0xB1>(pBa); pBa = dpp_xadd<0x4E>(pBa);                         \
    pBa = dpp_xadd<0x141>(pBa); pBa = dpp_xadd<0x140>(pBa);                       \
    float ezbA = EXP2F(fmaf(pBa, -1.44269504f, nb2));                             \
    float anbA = __builtin_amdgcn_rcpf(1.0f + ezbA);                              \
    float aj1A = __int_as_float(__builtin_amdgcn_readlane(__float_as_int(anbA), 48)); \
    if (DOSTORE) {                                                                \
      if (L < NSTATE) {                                                           \
        ob[L] = fmaf(aj0A, cact, vhiA);                                           \
        ob[L + 576] = fmaf(aj1A, cact, fmaf(aj0A, pcact, vloA));                  \
      }                                                                            \
      ob += 1152;                                                                 \
    }                                                                             \
    TWRAP(P);  /* before tbB, as in the original sequence */                      \
    float tbB = fmaf((float)((P) + 1), dtw, CBase);                               \
    float cloB = fmaf(TNX.x, C0.x, fmaf(TNX.y, C1.x, tbB));                       \
    cloB = fmaf(TIN.x, C2lo, cloB);                                               \
    cloB = fmaf(aj0A, F0.x, cloB);                                                \
    cloB = fmaf(aj1A, F1.x, cloB);                                                \
    float chiB = fmaf(TNX.x, C0.y, TNX.y * C1.y);                                 \
    chiB = fmaf(aj0A, F0.y, chiB);                                                \
    chiB = fmaf(aj1A, F1.y, chiB);                                                \
    v2f mB = bA + bB;                                                             \
    float vloB = mB.x + cloB, vhiB = mB.y + chiB;                                 \
    xbuf[wIdx] = vloB;                                                            \
    XI[0] = *(const v2f*)(xbuf + 0);  XI[1] = *(const v2f*)(xbuf + 2);            \
    XI[2] = *(const v2f*)(xbuf + 4);  XI[3] = *(const v2f*)(xbuf + 6);            \
    XI[4] = *(const v2f*)(xbuf + 8);  XI[5] = *(const v2f*)(xbuf + 10);           \
    XI[6] = *(const v2f*)(xbuf + 12); XI[7] = *(const v2f*)(xbuf + 14);           \
    XI[8] = *(const v2f*)(xbuf + 16);                                             \
    float aj0B, aj1B;                                                             \
    { POLICY(vloB, aj0B, aj1B); }                                                 \
    if (DOSTORE) {                                                                \
      if (L < NSTATE) {                                                           \
        ob[L] = fmaf(aj0B, cact, vhiB);                                           \
        ob[L + 576] = fmaf(aj1B, cact, fmaf(aj0B, pcact, vloB));                  \
      }                                                                            \
      ob += 1152;                                                                 \
    }                                                                             \
    a0p = aj0B; a1p = aj1B;                                                       \
    TWRAP((P) + 1);                                                               \
  } while (0)

// single-stream STEPP (fused fallback only) — R8-proven form.
#define STEPP(XI, XO, TIN, TNX, P, DOSTORE)                                       \
  do {                                                                            \
    TNX = *(const v2f*)(ldsT + 2 * (P) + 2);                                      \
    v2f accA; accA.x = 0.0f; accA.y = 0.0f;                                       \
    v2f accB; accB.x = 0.0f; accB.y = 0.0f;                                       \
    PKFMA_LO(accA, G[0],  XI[0]);  PKFMA_HI(accB, G[1],  XI[0]);                  \
    PKFMA_LO(accA, G[2],  XI[1]);  PKFMA_HI(accB, G[3],  XI[1]);                  \
    PKFMA_LO(accA, G[4],  XI[2]);  PKFMA_HI(accB, G[5],  XI[2]);                  \
    PKFMA_LO(accA, G[6],  XI[3]);  PKFMA_HI(accB, G[7],  XI[3]);                  \
    PKFMA_LO(accA, G[8],  XI[4]);  PKFMA_HI(accB, G[9],  XI[4]);                  \
    PKFMA_LO(accA, G[10], XI[5]);  PKFMA_HI(accB, G[11], XI[5]);                  \
    PKFMA_LO(accA, G[12], XI[6]);  PKFMA_HI(accB, G[13], XI[6]);                  \
    PKFMA_LO(accA, G[14], XI[7]);  PKFMA_HI(accB, G[15], XI[7]);                  \
    PKFMA_LO(accA, G[16], XI[8]);  PKFMA_HI(accB, G[17], XI[8]);                  \
    float tb = fmaf((float)(P), dtw, CBase);                                      \
    float clo = fmaf(TIN.x, C0.x, fmaf(TIN.y, C1.x, tb));                         \
    clo = fmaf(TNX.x, C2lo, clo);                                                 \
    clo = fmaf(a0p, F0.x, clo);                                                   \
    clo = fmaf(a1p, F1.x, clo);                                                   \
    float chi = fmaf(TIN.x, C0.y, TIN.y * C1.y);                                  \
    chi = fmaf(a0p, F0.y, chi);                                                   \
    chi = fmaf(a1p, F1.y, chi);                                                   \
    v2f acc = accA + accB;                                                        \
    float vlo = acc.x + clo, vhi = acc.y + chi;                                   \
    xbuf[wIdx] = vlo;                                                             \
    XO[0] = *(const v2f*)(xbuf + 0);  XO[1] = *(const v2f*)(xbuf + 2);            \
    XO[2] = *(const v2f*)(xbuf + 4);  XO[3] = *(const v2f*)(xbuf + 6);            \
    XO[4] = *(const v2f*)(xbuf + 8);  XO[5] = *(const v2f*)(xbuf + 10);           \
    XO[6] = *(const v2f*)(xbuf + 12); XO[7] = *(const v2f*)(xbuf + 14);           \
    XO[8] = *(const v2f*)(xbuf + 16);                                             \
    float aj0, aj1;                                                               \
    { POLICY(vlo, aj0, aj1); }                                                    \
    if (DOSTORE) {                                                                \
      if (L < NSTATE) {                                                           \
        ob[L] = fmaf(aj0, cact, vhi);                                             \
        ob[L + 576] = fmaf(aj1, cact, fmaf(aj0, pcact, vlo));                     \
      }                                                                            \
      ob += 1152;                                                                 \
    }                                                                             \
    a0p = aj0; a1p = aj1;                                                         \
  } while (0)

// fp64 Phi/constant construction, shared by setup kernel and fused kernel.
#define SETUP_BODY(DBp, WA, WB, W1, b1, w2, NT)                                    \
  double* A   = DBp;                                                               \
  double* A2  = DBp + 324;                                                         \
  double* A3  = DBp + 648;                                                         \
  double* A4  = DBp + 972;                                                         \
  double* bt  = DBp + 1296;                                                        \
  double* br  = DBp + 1314;                                                        \
  double* cv  = DBp + 1332;                                                        \
  double* d0v = DBp + 1350;                                                        \
  double* d1v = DBp + 1368;                                                        \
  double* pc1 = DBp + 1386;                                                        \
  double* pc2 = DBp + 1404;                                                        \
  double* pc3 = DBp + 1422;                                                        \
  const double dt = 30.0;                                                          \
  for (int t = L; t < 324; t += NT) {                                              \
    int i = t / 18, j = t % 18;                                                    \
    A[t] = 1e-4 * (double)WA[t] - (i == j ? 1e-3 : 0.0);                           \
  }                                                                                \
  if (L < NSTATE) {                                                                \
    bt[L] = 1e-6 * (double)WB[L * 17 + 0];                                         \
    double ssum = 0.0;                                                             \
    for (int c = 1; c < 17; ++c) ssum += (double)WB[L * 17 + c];                   \
    br[L] = -16914.0 * 1e-6 * ssum;                                                \
  }                                                                                \
  __syncthreads();                                                                 \
  for (int t = L; t < 324; t += NT) {                                              \
    int i = t / 18, j = t % 18;                                                    \
    double s2 = 0.0;                                                               \
    for (int l = 0; l < 18; ++l) s2 += A[i * 18 + l] * A[l * 18 + j];              \
    A2[t] = s2;                                                                    \
  }                                                                                \
  __syncthreads();                                                                 \
  for (int t = L; t < 324; t += NT) {                                              \
    int i = t / 18, j = t % 18;                                                    \
    double s3 = 0.0, s4 = 0.0;                                                     \
    for (int l = 0; l < 18; ++l) {                                                 \
      s3 += A2[i * 18 + l] * A[l * 18 + j];                                        \
      s4 += A2[i * 18 + l] * A2[l * 18 + j];                                       \
    }                                                                              \
    A3[t] = s3;                                                                    \
    A4[t] = s4;                                                                    \
  }                                                                                \
  __syncthreads();                                                                 \
  if (L < NSTATE) {                                                                \
    double sc = 0.0, dd0 = 0.0, dd1 = 0.0;                                         \
    for (int j = 0; j < 18; ++j) {                                                 \
      double m = (dt / 6.0) * ((L == j ? 6.0 : 0.0) + 3.0 * dt * A[L * 18 + j] +   \
                               dt * dt * A2[L * 18 + j] +                          \
                               0.25 * dt * dt * dt * A3[L * 18 + j]);              \
      sc += m * br[j];                                                             \
      double m1 = (dt / 6.0) * ((L == j ? 1.0 : 0.0) + dt * A[L * 18 + j] +        \
                                0.5 * dt * dt * A2[L * 18 + j] +                   \
                                0.25 * dt * dt * dt * A3[L * 18 + j]);             \
      double m23 = (dt / 6.0) * ((L == j ? 4.0 : 0.0) + 2.0 * dt * A[L * 18 + j] + \
                                 0.5 * dt * dt * A2[L * 18 + j]);                  \
      double m4 = (L == j ? dt / 6.0 : 0.0);                                       \
      dd0 += (m1 + 0.5 * m23) * bt[j];                                             \
      dd1 += (0.5 * m23 + m4) * bt[j];                                             \
    }                                                                              \
    cv[L] = sc;                                                                    \
    d0v[L] = dd0;                                                                  \
    d1v[L] = dd1;                                                                  \
  }                                                                                \
  __syncthreads();                                                                 \
  for (int t = L; t < 324; t += NT) {                                              \
    int i = t / 18, j = t % 18;                                                    \
    A[t] = (i == j ? 1.0 : 0.0) + dt * A[t] + (dt * dt / 2.0) * A2[t] +            \
           (dt * dt * dt / 6.0) * A3[t] + (dt * dt * dt * dt / 24.0) * A4[t];      \
  }                                                                                \
  __syncthreads();                                                                 \
  for (int t = L; t < 324; t += NT) {                                              \
    int i = t / 18, j = t % 18;                                                    \
    double s2 = 0.0;                                                               \
    for (int l = 0; l < 18; ++l) s2 += A[i * 18 + l] * A[l * 18 + j];              \
    A2[t] = s2;                                                                    \
  }                                                                                \
  __syncthreads();                                                                 \
  if (L < NSTATE) { double s1 = 0.0; for (int j = 0; j < 18; ++j) s1 += A[L * 18 + j] * cv[j];  pc1[L] = s1; } \
  __syncthreads();                                                                 \
  if (L < NSTATE) { double s1 = 0.0; for (int j = 0; j < 18; ++j) s1 += A[L * 18 + j] * pc1[j]; pc2[L] = s1; } \
  __syncthreads();                                                                 \
  if (L < NSTATE) { double s1 = 0.0; for (int j = 0; j < 18; ++j) s1 += A[L * 18 + j] * pc2[j]; pc3[L] = s1; } \
  __syncthreads();                                                                 \
  v2f G[18];                                                                       \
  v2f F0; F0.x = 0.f; F0.y = 0.f;                                                  \
  v2f F1; F1.x = 0.f; F1.y = 0.f;                                                  \
  v2f C0; C0.x = 0.f; C0.y = 0.f;                                                  \
  v2f C1; C1.x = 0.f; C1.y = 0.f;                                                  \
  float C2lo = 0.f, CWlo = 0.f, CTlo = 0.f, CBlo = 0.f;                            \
  float cact = 0.f, pcact = 0.f, uB = 0.f;                                         \
  float w2A = 0.f, nw2A = 0.f, w2B = 0.f, nw2B = 0.f;                              \
  if (L < NSTATE) {                                                                \
    for (int j = 0; j < 18; ++j) { G[j].x = (float)A2[L * 18 + j]; G[j].y = (float)A[L * 18 + j]; } \
    double pd0 = 0.0, pd1 = 0.0;                                                   \
    for (int j = 0; j < 18; ++j) { pd0 += A[L * 18 + j] * d0v[j]; pd1 += A[L * 18 + j] * d1v[j]; } \
    C0.x = (float)pd0;            C0.y = (float)d0v[L];                            \
    C1.x = (float)(pd1 + d0v[L]); C1.y = (float)d1v[L];                            \
    C2lo = (float)d1v[L];                                                          \
    F0.x = (float)pc3[L]; F0.y = (float)pc2[L];                                    \
    F1.x = (float)pc2[L]; F1.y = (float)pc1[L];                                    \
    cact = (float)cv[L];                                                           \
    pcact = (float)pc1[L];                                                         \
  } else if (L >= 32 && L < 48) {                                                  \
    int m = L - 32;                                                                \
    double f0 = 0.0, f1 = 0.0, ssum = 0.0;                                         \
    for (int j = 0; j < 18; ++j) {                                                 \
      double g = (double)W1[m * 20 + j] * ((double)PS / 1.41);                     \
      G[j].x = (float)g; G[j].y = 0.f;                                             \
      f0 += g * pc1[j];                                                            \
      f1 += g * cv[j];                                                             \
      ssum += (double)W1[m * 20 + j];                                              \
    }                                                                              \
    F0.x = (float)f0; F1.x = (float)f1;                                            \
    CBlo = (float)(((double)b1[m] - ssum * (23.359 / 1.41)) * (double)PS);         \
    CWlo = W1[m * 20 + 18] * PS * (1.0f / 604800.0f);                              \
    CTlo = W1[m * 20 + 19] * PS * (1.0f / 86400.0f);                               \
    w2A = w2[m]; nw2A = -2.0f * w2A;                                               \
  } else if (L >= 48 && L < 64) {                                                  \
    int m = L - 48;                                                                \
    double f0 = 0.0, f1 = 0.0, ub = 0.0, ssum = 0.0, wd0 = 0.0, wd1 = 0.0;         \
    for (int j = 0; j < 18; ++j) {                                                 \
      double g = (double)W1[m * 20 + j] * ((double)PS / 1.41);                     \
      double wp = 0.0;                                                             \
      for (int k = 0; k < 18; ++k)                                                 \
        wp += (double)W1[m * 20 + k] * ((double)PS / 1.41) * A[k * 18 + j];        \
      G[j].x = (float)wp; G[j].y = 0.f;                                            \
      f0 += g * pc2[j];                                                            \
      f1 += g * pc1[j];                                                            \
      ub += g * cv[j];                                                             \
      wd0 += g * d0v[j];                                                           \
      wd1 += g * d1v[j];                                                           \
      ssum += (double)W1[m * 20 + j];                                              \
    }                                                                              \
    F0.x = (float)f0; F1.x = (float)f1; uB = (float)ub;                            \
    C0.x = (float)wd0; C1.x = (float)wd1;                                          \
    CWlo = W1[m * 20 + 18] * PS * (1.0f / 604800.0f);                              \
    CTlo = W1[m * 20 + 19] * PS * (1.0f / 86400.0f);                               \
    CBlo = (float)(((double)b1[m] - ssum * (23.359 / 1.41)) * (double)PS) +        \
           30.0f * CWlo + 30.0f * CTlo;                                            \
    w2B = w2[m]; nw2B = -2.0f * w2B;                                               \
  } else {                                                                         \
    for (int j = 0; j < 18; ++j) { G[j].x = 0.f; G[j].y = 0.f; }                   \
  }

// common per-lane time-base setup from kb.
#define TIME_BASE_SETUP(kbv)                                                       \
  const unsigned ft0u = (30u * (unsigned)(kbv)) % 86400u;                          \
  const unsigned fw0u = (518400u + 30u * (unsigned)(kbv)) % 604800u;               \
  const int pD = (int)((86400u - ft0u + 59u) / 60u);                               \
  const int pW = (int)((604800u - fw0u + 59u) / 60u);                              \
  float CBase = fmaf((float)ft0u, CTlo, fmaf((float)fw0u, CWlo, CBlo));            \
  const float dtw = fmaf(60.0f, CTlo, 60.0f * CWlo);                               \
  const float dayCorr = 86400.0f * CTlo;                                           \
  const float weekCorr = 604800.0f * CWlo;

// ---------------------------------------------------------------------------
// Setup kernel (split path): runs ONCE. Per-lane constants + quasi-static
// vectors (Jacobi, wave-0 only, no barriers — R12/R13-proven).
//   ws[0..3519]  : per-lane constants   ws[3520+L]: v_t[L]   ws[3584+L]: v_r[L]
// ---------------------------------------------------------------------------
__global__ __launch_bounds__(256) void rc_setup(
    const float* __restrict__ WA, const float* __restrict__ WB,
    const float* __restrict__ W1, const float* __restrict__ b1,
    const float* __restrict__ w2, float* __restrict__ wsf) {
  __shared__ double DB[1440];
  __shared__ double vt[18], vr[18];
  const int L = threadIdx.x;
  const float PS = 2.88539008f;  // 2*log2(e)
  SETUP_BODY(DB, WA, WB, W1, b1, w2, 256);

  if (L < 64) {
#pragma unroll
    for (int j = 0; j < 18; ++j) *(v2f*)(wsf + j * 128 + 2 * L) = G[j];
    *(v2f*)(wsf + 2304 + 0 * 128 + 2 * L) = F0;
    *(v2f*)(wsf + 2304 + 1 * 128 + 2 * L) = F1;
    *(v2f*)(wsf + 2304 + 2 * 128 + 2 * L) = C0;
    *(v2f*)(wsf + 2304 + 3 * 128 + 2 * L) = C1;
    float* scp = wsf + 2816;
    scp[0 * 64 + L] = C2lo;  scp[1 * 64 + L] = CWlo;  scp[2 * 64 + L] = CTlo;
    scp[3 * 64 + L] = CBlo;  scp[4 * 64 + L] = cact;  scp[5 * 64 + L] = pcact;
    scp[6 * 64 + L] = uB;    scp[7 * 64 + L] = w2A;   scp[8 * 64 + L] = nw2A;
    scp[9 * 64 + L] = w2B;   scp[10 * 64 + L] = nw2B;

    // ---- quasi-static vectors: wave-0 only, in-wave DS ordering ----
    if (L < 18) { vt[L] = 1000.0 * bt[L]; vr[L] = 1000.0 * br[L]; }
    for (int it = 0; it < 16; ++it) {
      double st = 0.0, sr = 0.0;
      if (L < 18) {
        for (int j = 0; j < 18; ++j) {
          double w = (double)WA[L * 18 + j];
          st += w * vt[j];
          sr += w * vr[j];
        }
        vt[L] = 1000.0 * bt[L] + 0.1 * st;
        vr[L] = 1000.0 * br[L] + 0.1 * sr;
      }
    }
    if (L < 18) {
      wsf[3520 + L] = (float)vt[L];
      wsf[3584 + L] = (float)vr[L];
    }
  }
}

// ---------------------------------------------------------------------------
// Run kernel (split path): R8 geometry, R13 qs-init + BURN=160, NEW fused
// STEPPAIR with policy/matvec source-level interleave.
// ---------------------------------------------------------------------------
__global__ __launch_bounds__(64, 4) void rc_run(
    const float* __restrict__ ws, const float* __restrict__ b2,
    const float* __restrict__ iv, const float* __restrict__ tout,
    float* __restrict__ out) {
  __shared__ float ldsT[BURN + RSEGLEN + 2];   // 418 floats
  __shared__ __align__(16) float xbuf[96];

  const int L = threadIdx.x;
  const int idx = blockIdx.x;
  const int b = idx & (NBATCH - 1);
  const int s = idx >> 5;

  const int ks = (s == RSEGS - 1) ? (TSTEPS - 1 - RSEGLEN) : s * RSEGLEN;
  const int kb = max(0, ks - BURN);
  const int mBurn = ks - kb;        // 0 or 160
  const int mEnd = (ks + RSEGLEN) - kb;

  // ---- per-lane constants: coalesced loads from workspace ----
  v2f G[18];
#pragma unroll
  for (int j = 0; j < 18; ++j) G[j] = *(const v2f*)(ws + j * 128 + 2 * L);
  v2f F0 = *(const v2f*)(ws + 2304 + 0 * 128 + 2 * L);
  v2f F1 = *(const v2f*)(ws + 2304 + 1 * 128 + 2 * L);
  v2f C0 = *(const v2f*)(ws + 2304 + 2 * 128 + 2 * L);
  v2f C1 = *(const v2f*)(ws + 2304 + 3 * 128 + 2 * L);
  const float* scp = ws + 2816;
  const float C2lo = scp[0 * 64 + L], CWlo = scp[1 * 64 + L];
  const float CTlo = scp[2 * 64 + L], CBlo = scp[3 * 64 + L];
  const float cact = scp[4 * 64 + L], pcact = scp[5 * 64 + L];
  const float uB   = scp[6 * 64 + L];
  const float w2A  = scp[7 * 64 + L], nw2A = scp[8 * 64 + L];
  const float w2B  = scp[9 * 64 + L], nw2B = scp[10 * 64 + L];
  const float nb2 = -1.44269504f * b2[0];

  TIME_BASE_SETUP(kb);

  // ---- stage tout slice ----
  const int cnt = mEnd + 2;   // up to 418
  for (int i = L; i < cnt; i += 64) ldsT[i] = tout[kb + i];
  __syncthreads();

  // ---- state init: s=0 exact iv; s>0 quasi-static estimate ----
  float q = 0.0f;
  if (L < NSTATE) {
    float qiv = iv[b * NSTATE + L];
    if (s == 0) {
      q = qiv;
    } else {
      float x0 = fmaf(ldsT[0], ws[3520 + L], 0.5f * ws[3584 + L]);
      q = (__builtin_fabsf(x0) < 1.0e4f) ? x0 : qiv;  // NaN/Inf/garbage guard
    }
  }
  if (s == 0 && L < NSTATE) out[b * NSTATE + L] = q;

  float a0p = (s == 0) ? 0.0f : 0.5f;
  float a1p = a0p;

  float* ob = out + (size_t)(ks + 1) * (NBATCH * NSTATE) + b * NSTATE;

  const int wIdx = (L < NSTATE) ? L : (32 + L);
  xbuf[wIdx] = q;               // single-wave block: in-order DS makes this safe
  v2f X[9], Y[9];
#pragma unroll
  for (int j = 0; j < 9; ++j) X[j] = *(const v2f*)(xbuf + 2 * j);

  v2f tU, tV;
  tU.x = ldsT[0]; tU.y = ldsT[1];

  const int nburn = mBurn >> 1;              // 0 or 80 pairs (even)
  const int ntot = mEnd >> 1;                // nburn + 128 pairs
  int p = 0;
  for (; p < nburn; p += 2) {
    STEPPAIR(X, Y, tU, tV, p, false);
  }
  for (; p < ntot; p += 2) {                 // 64 store pair-iterations
    STEPPAIR(X, Y, tU, tV, p, true);
  }
}

// ---------------------------------------------------------------------------
// Fused fallback: single-stream R8 form with iv-init, FBURN=176.
// Used only when workspace is unusable.
// ---------------------------------------------------------------------------
__global__ __launch_bounds__(64, 2) void rc_fused(
    const float* __restrict__ WA, const float* __restrict__ WB,
    const float* __restrict__ W1, const float* __restrict__ b1,
    const float* __restrict__ w2, const float* __restrict__ b2,
    const float* __restrict__ iv, const float* __restrict__ tout,
    float* __restrict__ out) {
  __shared__ double DB[1440];
  __shared__ __align__(16) float xbuf[96];

  const int L = threadIdx.x;
  const int idx = blockIdx.x;
  const int b = idx & (NBATCH - 1);
  const int s = idx >> 5;
  const float PS = 2.88539008f;  // 2*log2(e)

  const int ks = (s == FSEGS - 1) ? (TSTEPS - 1 - FSEGLEN) : s * FSEGLEN;
  const int kb = max(0, ks - FBURN);
  const int mBurn = ks - kb;
  const int mEnd = (ks + FSEGLEN) - kb;

  SETUP_BODY(DB, WA, WB, W1, b1, w2, 64);
  const float b2v = b2[0];
  const float nb2 = -1.44269504f * b2v;
  TIME_BASE_SETUP(kb);
  __syncthreads();

  float* ldsT = (float*)DB;
  const int cnt = mEnd + 2;
  for (int i = L; i < cnt; i += 64) ldsT[i] = tout[kb + i];
  __syncthreads();

  float q = (L < NSTATE) ? iv[b * NSTATE + L] : 0.0f;
  if (s == 0 && L < NSTATE) out[b * NSTATE + L] = q;

  float a0p = 0.0f, a1p = 0.0f;

  float* ob = out + (size_t)(ks + 1) * (NBATCH * NSTATE) + b * NSTATE;

  const int wIdx = (L < NSTATE) ? L : (32 + L);
  xbuf[wIdx] = q;
  v2f X[9], Y[9];
#pragma unroll
  for (int j = 0; j < 9; ++j) X[j] = *(const v2f*)(xbuf + 2 * j);

  v2f tU, tV;
  tU.x = ldsT[0]; tU.y = ldsT[1];

  const int nburn = mBurn >> 1;
  const int ntot = mEnd >> 1;
  int p = 0;
  for (; p < nburn; p += 2) {
    STEPP(X, Y, tU, tV, p, false);     TWRAP(p);
    STEPP(Y, X, tV, tU, p + 1, false); TWRAP(p + 1);
  }
  for (; p < ntot; p += 2) {
    STEPP(X, Y, tU, tV, p, true);      TWRAP(p);
    STEPP(Y, X, tV, tU, p + 1, true);  TWRAP(p + 1);
  }
}

extern "C" void kernel_launch(void* const* d_in, const int* in_sizes, int n_in,
                              void* d_out, int out_size, void* d_ws, size_t ws_size,
                              hipStream_t stream) {
  // inputs: 0=t_eval 1=iv 2=W_A 3=W_B 4=W1 5=b1 6=w2 7=b2 8=Tout_table
  const float* iv = (const float*)d_in[1];
  const float* WA = (const float*)d_in[2];
  const float* WB = (const float*)d_in[3];
  const float* W1 = (const float*)d_in[4];
  const float* b1 = (const float*)d_in[5];
  const float* w2 = (const float*)d_in[6];
  const float* b2 = (const float*)d_in[7];
  const float* tout = (const float*)d_in[8];
  float* out = (float*)d_out;

  if (d_ws != nullptr && ws_size >= 14464) {
    float* wsf = (float*)d_ws;
    rc_setup<<<1, 256, 0, stream>>>(WA, WB, W1, b1, w2, wsf);
    rc_run<<<NBATCH * RSEGS, 64, 0, stream>>>(wsf, b2, iv, tout, out);
  } else {
    rc_fused<<<NBATCH * FSEGS, 64, 0, stream>>>(WA, WB, W1, b1, w2, b2, iv, tout, out);
  }
}

// Round 15
// 225.768 us; speedup vs baseline: 1.0201x; 1.0201x over previous
//
#include <hip/hip_runtime.h>

#define NSTATE 18
#define NBATCH 32
#define TSTEPS 32768
#define BURN   148    // qs-init decay measured: 136->5.0, 160->3.0, 176->2.0.
                      // local rate 0.975-0.979/step; 148 (mid-bracket interp)
                      // -> 5.0*0.979^12 ~= 3.9 < 4.6 (pessimistic 0.989 -> 4.4)

// split-path geometry (R8-proven optimum)
#define RSEGS   128
#define RSEGLEN 256
// fused-fallback geometry (iv-init -> needs more burn)
#define FBURN   176
#define FSEGS   64
#define FSEGLEN 512

typedef float v2f __attribute__((ext_vector_type(2)));

// native single-instruction exp2 (v_exp_f32, <=1 ULP) — R5's win.
#define EXP2F(x) __builtin_amdgcn_exp2f(x)

// packed fp32 FMA with op_sel broadcast of src1 (X) halves.
#define PKFMA_LO(ACC, Gp, Xp) \
  asm("v_pk_fma_f32 %0, %1, %2, %0 op_sel:[0,0,0] op_sel_hi:[1,0,1]" \
      : "+v"(ACC) : "v"(Gp), "v"(Xp))
#define PKFMA_HI(ACC, Gp, Xp) \
  asm("v_pk_fma_f32 %0, %1, %2, %0 op_sel:[0,1,0] op_sel_hi:[1,1,1]" \
      : "+v"(ACC) : "v"(Gp), "v"(Xp))

// butterfly-sum level: mov_dpp + add, compiler-scheduled.
template <int CTRL>
__device__ __forceinline__ float dpp_xadd(float x) {
  int y = __builtin_amdgcn_update_dpp(0, __float_as_int(x), CTRL, 0xF, 0xF, true);
  return x + __int_as_float(y);
}

// policy evaluation chain: vlo -> (aj0, aj1).
#define POLICY(VLO, AJ0, AJ1)                                                     \
    float e2_ = EXP2F(VLO);                                                       \
    float rc_ = __builtin_amdgcn_rcpf(1.0f + e2_);                                \
    float pA_ = fmaf(nw2A, rc_, w2A);                                             \
    pA_ = dpp_xadd<0xB1>(pA_); pA_ = dpp_xadd<0x4E>(pA_);                         \
    pA_ = dpp_xadd<0x141>(pA_); pA_ = dpp_xadd<0x140>(pA_);                       \
    float ez_ = EXP2F(fmaf(pA_, -1.44269504f, nb2));                              \
    float an_ = __builtin_amdgcn_rcpf(1.0f + ez_);                                \
    AJ0 = __int_as_float(__builtin_amdgcn_readlane(__float_as_int(an_), 32));     \
    float qB_ = fmaf(AJ0, uB, VLO);                                               \
    float e2b_ = EXP2F(qB_);                                                      \
    float rcb_ = __builtin_amdgcn_rcpf(1.0f + e2b_);                              \
    float pB_ = fmaf(nw2B, rcb_, w2B);                                            \
    pB_ = dpp_xadd<0xB1>(pB_); pB_ = dpp_xadd<0x4E>(pB_);                         \
    pB_ = dpp_xadd<0x141>(pB_); pB_ = dpp_xadd<0x140>(pB_);                       \
    float ezb_ = EXP2F(fmaf(pB_, -1.44269504f, nb2));                             \
    float anb_ = __builtin_amdgcn_rcpf(1.0f + ezb_);                              \
    AJ1 = __int_as_float(__builtin_amdgcn_readlane(__float_as_int(anb_), 48))

// wave-uniform wrap correction (R8-proven).
#define TWRAP(P)                                                                  \
  do {                                                                            \
    if ((P) + 1 == pD) CBase -= dayCorr;                                          \
    if ((P) + 1 == pW) CBase -= weekCorr;                                         \
  } while (0)

// ---------------------------------------------------------------------------
// FUSED DOUBLE-STEP PAIR (steps P and P+1): numerically identical to
// STEPP(XI->XM,P) ; TWRAP(P) ; STEPP(XM->XI,P+1) ; TWRAP(P+1), with policy-A's
// chain textually interleaved with matvec-B (R14: +1% — kept).
// ---------------------------------------------------------------------------
#define STEPPAIR(XI, XM, TIN, TNX, P, DOSTORE)                                    \
  do {                                                                            \
    TNX = *(const v2f*)(ldsT + 2 * (P) + 2);                                      \
    v2f aA; aA.x = 0.0f; aA.y = 0.0f;                                             \
    v2f aB; aB.x = 0.0f; aB.y = 0.0f;                                             \
    PKFMA_LO(aA, G[0],  XI[0]);  PKFMA_HI(aB, G[1],  XI[0]);                      \
    PKFMA_LO(aA, G[2],  XI[1]);  PKFMA_HI(aB, G[3],  XI[1]);                      \
    PKFMA_LO(aA, G[4],  XI[2]);  PKFMA_HI(aB, G[5],  XI[2]);                      \
    PKFMA_LO(aA, G[6],  XI[3]);  PKFMA_HI(aB, G[7],  XI[3]);                      \
    PKFMA_LO(aA, G[8],  XI[4]);  PKFMA_HI(aB, G[9],  XI[4]);                      \
    PKFMA_LO(aA, G[10], XI[5]);  PKFMA_HI(aB, G[11], XI[5]);                      \
    PKFMA_LO(aA, G[12], XI[6]);  PKFMA_HI(aB, G[13], XI[6]);                      \
    PKFMA_LO(aA, G[14], XI[7]);  PKFMA_HI(aB, G[15], XI[7]);                      \
    PKFMA_LO(aA, G[16], XI[8]);  PKFMA_HI(aB, G[17], XI[8]);                      \
    float tbA = fmaf((float)(P), dtw, CBase);                                     \
    float cloA = fmaf(TIN.x, C0.x, fmaf(TIN.y, C1.x, tbA));                       \
    cloA = fmaf(TNX.x, C2lo, cloA);                                               \
    cloA = fmaf(a0p, F0.x, cloA);                                                 \
    cloA = fmaf(a1p, F1.x, cloA);                                                 \
    float chiA = fmaf(TIN.x, C0.y, TIN.y * C1.y);                                 \
    chiA = fmaf(a0p, F0.y, chiA);                                                 \
    chiA = fmaf(a1p, F1.y, chiA);                                                 \
    v2f mA = aA + aB;                                                             \
    float vloA = mA.x + cloA, vhiA = mA.y + chiA;                                 \
    xbuf[wIdx] = vloA; /* in-order DS per wave: lands before the reads */         \
    XM[0] = *(const v2f*)(xbuf + 0);  XM[1] = *(const v2f*)(xbuf + 2);            \
    XM[2] = *(const v2f*)(xbuf + 4);  XM[3] = *(const v2f*)(xbuf + 6);            \
    XM[4] = *(const v2f*)(xbuf + 8);  XM[5] = *(const v2f*)(xbuf + 10);           \
    XM[6] = *(const v2f*)(xbuf + 12); XM[7] = *(const v2f*)(xbuf + 14);           \
    XM[8] = *(const v2f*)(xbuf + 16);                                             \
    TIN = *(const v2f*)(ldsT + 2 * (P) + 4); /* step-B t2 + next pair's TIN */    \
    /* ---- interleave: policy-A chain || matvec-B on XM ---- */                  \
    v2f bA; bA.x = 0.0f; bA.y = 0.0f;                                             \
    v2f bB; bB.x = 0.0f; bB.y = 0.0f;                                             \
    float e2A = EXP2F(vloA);                                                      \
    PKFMA_LO(bA, G[0],  XM[0]);  PKFMA_HI(bB, G[1],  XM[0]);                      \
    float rcA = __builtin_amdgcn_rcpf(1.0f + e2A);                                \
    PKFMA_LO(bA, G[2],  XM[1]);  PKFMA_HI(bB, G[3],  XM[1]);                      \
    float pAa = fmaf(nw2A, rcA, w2A);                                             \
    PKFMA_LO(bA, G[4],  XM[2]);  PKFMA_HI(bB, G[5],  XM[2]);                      \
    pAa = dpp_xadd<0xB1>(pAa);                                                    \
    PKFMA_LO(bA, G[6],  XM[3]);  PKFMA_HI(bB, G[7],  XM[3]);                      \
    pAa = dpp_xadd<0x4E>(pAa);                                                    \
    PKFMA_LO(bA, G[8],  XM[4]);  PKFMA_HI(bB, G[9],  XM[4]);                      \
    pAa = dpp_xadd<0x141>(pAa);                                                   \
    PKFMA_LO(bA, G[10], XM[5]);  PKFMA_HI(bB, G[11], XM[5]);                      \
    pAa = dpp_xadd<0x140>(pAa);                                                   \
    PKFMA_LO(bA, G[12], XM[6]);  PKFMA_HI(bB, G[13], XM[6]);                      \
    float ezA = EXP2F(fmaf(pAa, -1.44269504f, nb2));                              \
    PKFMA_LO(bA, G[14], XM[7]);  PKFMA_HI(bB, G[15], XM[7]);                      \
    float anA = __builtin_amdgcn_rcpf(1.0f + ezA);                                \
    PKFMA_LO(bA, G[16], XM[8]);  PKFMA_HI(bB, G[17], XM[8]);                      \
    float aj0A = __int_as_float(__builtin_amdgcn_readlane(__float_as_int(anA), 32)); \
    float qBA = fmaf(aj0A, uB, vloA);                                             \
    float e2bA = EXP2F(qBA);                                                      \
    float rcbA = __builtin_amdgcn_rcpf(1.0f + e2bA);                              \
    float pBa = fmaf(nw2B, rcbA, w2B);                                            \
    pBa = dpp_xadd<0xB1>(pBa); pBa = dpp_xadd<0x4E>(pBa);                         \
    pBa = dpp_xadd<0x141>(pBa); pBa = dpp_xadd<0x140>(pBa);                       \
    float ezbA = EXP2F(fmaf(pBa, -1.44269504f, nb2));                             \
    float anbA = __builtin_amdgcn_rcpf(1.0f + ezbA);                              \
    float aj1A = __int_as_float(__builtin_amdgcn_readlane(__float_as_int(anbA), 48)); \
    if (DOSTORE) {                                                                \
      if (L < NSTATE) {                                                           \
        ob[L] = fmaf(aj0A, cact, vhiA);                                           \
        ob[L + 576] = fmaf(aj1A, cact, fmaf(aj0A, pcact, vloA));                  \
      }                                                                            \
      ob += 1152;                                                                 \
    }                                                                             \
    TWRAP(P);  /* before tbB, as in the original sequence */                      \
    float tbB = fmaf((float)((P) + 1), dtw, CBase);                               \
    float cloB = fmaf(TNX.x, C0.x, fmaf(TNX.y, C1.x, tbB));                       \
    cloB = fmaf(TIN.x, C2lo, cloB);                                               \
    cloB = fmaf(aj0A, F0.x, cloB);                                                \
    cloB = fmaf(aj1A, F1.x, cloB);                                                \
    float chiB = fmaf(TNX.x, C0.y, TNX.y * C1.y);                                 \
    chiB = fmaf(aj0A, F0.y, chiB);                                                \
    chiB = fmaf(aj1A, F1.y, chiB);                                                \
    v2f mB = bA + bB;                                                             \
    float vloB = mB.x + cloB, vhiB = mB.y + chiB;                                 \
    xbuf[wIdx] = vloB;                                                            \
    XI[0] = *(const v2f*)(xbuf + 0);  XI[1] = *(const v2f*)(xbuf + 2);            \
    XI[2] = *(const v2f*)(xbuf + 4);  XI[3] = *(const v2f*)(xbuf + 6);            \
    XI[4] = *(const v2f*)(xbuf + 8);  XI[5] = *(const v2f*)(xbuf + 10);           \
    XI[6] = *(const v2f*)(xbuf + 12); XI[7] = *(const v2f*)(xbuf + 14);           \
    XI[8] = *(const v2f*)(xbuf + 16);                                             \
    float aj0B, aj1B;                                                             \
    { POLICY(vloB, aj0B, aj1B); }                                                 \
    if (DOSTORE) {                                                                \
      if (L < NSTATE) {                                                           \
        ob[L] = fmaf(aj0B, cact, vhiB);                                           \
        ob[L + 576] = fmaf(aj1B, cact, fmaf(aj0B, pcact, vloB));                  \
      }                                                                            \
      ob += 1152;                                                                 \
    }                                                                             \
    a0p = aj0B; a1p = aj1B;                                                       \
    TWRAP((P) + 1);                                                               \
  } while (0)

// single-stream STEPP (fused fallback only) — R8-proven form.
#define STEPP(XI, XO, TIN, TNX, P, DOSTORE)                                       \
  do {                                                                            \
    TNX = *(const v2f*)(ldsT + 2 * (P) + 2);                                      \
    v2f accA; accA.x = 0.0f; accA.y = 0.0f;                                       \
    v2f accB; accB.x = 0.0f; accB.y = 0.0f;                                       \
    PKFMA_LO(accA, G[0],  XI[0]);  PKFMA_HI(accB, G[1],  XI[0]);                  \
    PKFMA_LO(accA, G[2],  XI[1]);  PKFMA_HI(accB, G[3],  XI[1]);                  \
    PKFMA_LO(accA, G[4],  XI[2]);  PKFMA_HI(accB, G[5],  XI[2]);                  \
    PKFMA_LO(accA, G[6],  XI[3]);  PKFMA_HI(accB, G[7],  XI[3]);                  \
    PKFMA_LO(accA, G[8],  XI[4]);  PKFMA_HI(accB, G[9],  XI[4]);                  \
    PKFMA_LO(accA, G[10], XI[5]);  PKFMA_HI(accB, G[11], XI[5]);                  \
    PKFMA_LO(accA, G[12], XI[6]);  PKFMA_HI(accB, G[13], XI[6]);                  \
    PKFMA_LO(accA, G[14], XI[7]);  PKFMA_HI(accB, G[15], XI[7]);                  \
    PKFMA_LO(accA, G[16], XI[8]);  PKFMA_HI(accB, G[17], XI[8]);                  \
    float tb = fmaf((float)(P), dtw, CBase);                                      \
    float clo = fmaf(TIN.x, C0.x, fmaf(TIN.y, C1.x, tb));                         \
    clo = fmaf(TNX.x, C2lo, clo);                                                 \
    clo = fmaf(a0p, F0.x, clo);                                                   \
    clo = fmaf(a1p, F1.x, clo);                                                   \
    float chi = fmaf(TIN.x, C0.y, TIN.y * C1.y);                                  \
    chi = fmaf(a0p, F0.y, chi);                                                   \
    chi = fmaf(a1p, F1.y, chi);                                                   \
    v2f acc = accA + accB;                                                        \
    float vlo = acc.x + clo, vhi = acc.y + chi;                                   \
    xbuf[wIdx] = vlo;                                                             \
    XO[0] = *(const v2f*)(xbuf + 0);  XO[1] = *(const v2f*)(xbuf + 2);            \
    XO[2] = *(const v2f*)(xbuf + 4);  XO[3] = *(const v2f*)(xbuf + 6);            \
    XO[4] = *(const v2f*)(xbuf + 8);  XO[5] = *(const v2f*)(xbuf + 10);           \
    XO[6] = *(const v2f*)(xbuf + 12); XO[7] = *(const v2f*)(xbuf + 14);           \
    XO[8] = *(const v2f*)(xbuf + 16);                                             \
    float aj0, aj1;                                                               \
    { POLICY(vlo, aj0, aj1); }                                                    \
    if (DOSTORE) {                                                                \
      if (L < NSTATE) {                                                           \
        ob[L] = fmaf(aj0, cact, vhi);                                             \
        ob[L + 576] = fmaf(aj1, cact, fmaf(aj0, pcact, vlo));                     \
      }                                                                            \
      ob += 1152;                                                                 \
    }                                                                             \
    a0p = aj0; a1p = aj1;                                                         \
  } while (0)

// fp64 Phi/constant construction, shared by setup kernel and fused kernel.
#define SETUP_BODY(DBp, WA, WB, W1, b1, w2, NT)                                    \
  double* A   = DBp;                                                               \
  double* A2  = DBp + 324;                                                         \
  double* A3  = DBp + 648;                                                         \
  double* A4  = DBp + 972;                                                         \
  double* bt  = DBp + 1296;                                                        \
  double* br  = DBp + 1314;                                                        \
  double* cv  = DBp + 1332;                                                        \
  double* d0v = DBp + 1350;                                                        \
  double* d1v = DBp + 1368;                                                        \
  double* pc1 = DBp + 1386;                                                        \
  double* pc2 = DBp + 1404;                                                        \
  double* pc3 = DBp + 1422;                                                        \
  const double dt = 30.0;                                                          \
  for (int t = L; t < 324; t += NT) {                                              \
    int i = t / 18, j = t % 18;                                                    \
    A[t] = 1e-4 * (double)WA[t] - (i == j ? 1e-3 : 0.0);                           \
  }                                                                                \
  if (L < NSTATE) {                                                                \
    bt[L] = 1e-6 * (double)WB[L * 17 + 0];                                         \
    double ssum = 0.0;                                                             \
    for (int c = 1; c < 17; ++c) ssum += (double)WB[L * 17 + c];                   \
    br[L] = -16914.0 * 1e-6 * ssum;                                                \
  }                                                                                \
  __syncthreads();                                                                 \
  for (int t = L; t < 324; t += NT) {                                              \
    int i = t / 18, j = t % 18;                                                    \
    double s2 = 0.0;                                                               \
    for (int l = 0; l < 18; ++l) s2 += A[i * 18 + l] * A[l * 18 + j];              \
    A2[t] = s2;                                                                    \
  }                                                                                \
  __syncthreads();                                                                 \
  for (int t = L; t < 324; t += NT) {                                              \
    int i = t / 18, j = t % 18;                                                    \
    double s3 = 0.0, s4 = 0.0;                                                     \
    for (int l = 0; l < 18; ++l) {                                                 \
      s3 += A2[i * 18 + l] * A[l * 18 + j];                                        \
      s4 += A2[i * 18 + l] * A2[l * 18 + j];                                       \
    }                                                                              \
    A3[t] = s3;                                                                    \
    A4[t] = s4;                                                                    \
  }                                                                                \
  __syncthreads();                                                                 \
  if (L < NSTATE) {                                                                \
    double sc = 0.0, dd0 = 0.0, dd1 = 0.0;                                         \
    for (int j = 0; j < 18; ++j) {                                                 \
      double m = (dt / 6.0) * ((L == j ? 6.0 : 0.0) + 3.0 * dt * A[L * 18 + j] +   \
                               dt * dt * A2[L * 18 + j] +                          \
                               0.25 * dt * dt * dt * A3[L * 18 + j]);              \
      sc += m * br[j];                                                             \
      double m1 = (dt / 6.0) * ((L == j ? 1.0 : 0.0) + dt * A[L * 18 + j] +        \
                                0.5 * dt * dt * A2[L * 18 + j] +                   \
                                0.25 * dt * dt * dt * A3[L * 18 + j]);             \
      double m23 = (dt / 6.0) * ((L == j ? 4.0 : 0.0) + 2.0 * dt * A[L * 18 + j] + \
                                 0.5 * dt * dt * A2[L * 18 + j]);                  \
      double m4 = (L == j ? dt / 6.0 : 0.0);                                       \
      dd0 += (m1 + 0.5 * m23) * bt[j];                                             \
      dd1 += (0.5 * m23 + m4) * bt[j];                                             \
    }                                                                              \
    cv[L] = sc;                                                                    \
    d0v[L] = dd0;                                                                  \
    d1v[L] = dd1;                                                                  \
  }                                                                                \
  __syncthreads();                                                                 \
  for (int t = L; t < 324; t += NT) {                                              \
    int i = t / 18, j = t % 18;                                                    \
    A[t] = (i == j ? 1.0 : 0.0) + dt * A[t] + (dt * dt / 2.0) * A2[t] +            \
           (dt * dt * dt / 6.0) * A3[t] + (dt * dt * dt * dt / 24.0) * A4[t];      \
  }                                                                                \
  __syncthreads();                                                                 \
  for (int t = L; t < 324; t += NT) {                                              \
    int i = t / 18, j = t % 18;                                                    \
    double s2 = 0.0;                                                               \
    for (int l = 0; l < 18; ++l) s2 += A[i * 18 + l] * A[l * 18 + j];              \
    A2[t] = s2;                                                                    \
  }                                                                                \
  __syncthreads();                                                                 \
  if (L < NSTATE) { double s1 = 0.0; for (int j = 0; j < 18; ++j) s1 += A[L * 18 + j] * cv[j];  pc1[L] = s1; } \
  __syncthreads();                                                                 \
  if (L < NSTATE) { double s1 = 0.0; for (int j = 0; j < 18; ++j) s1 += A[L * 18 + j] * pc1[j]; pc2[L] = s1; } \
  __syncthreads();                                                                 \
  if (L < NSTATE) { double s1 = 0.0; for (int j = 0; j < 18; ++j) s1 += A[L * 18 + j] * pc2[j]; pc3[L] = s1; } \
  __syncthreads();                                                                 \
  v2f G[18];                                                                       \
  v2f F0; F0.x = 0.f; F0.y = 0.f;                                                  \
  v2f F1; F1.x = 0.f; F1.y = 0.f;                                                  \
  v2f C0; C0.x = 0.f; C0.y = 0.f;                                                  \
  v2f C1; C1.x = 0.f; C1.y = 0.f;                                                  \
  float C2lo = 0.f, CWlo = 0.f, CTlo = 0.f, CBlo = 0.f;                            \
  float cact = 0.f, pcact = 0.f, uB = 0.f;                                         \
  float w2A = 0.f, nw2A = 0.f, w2B = 0.f, nw2B = 0.f;                              \
  if (L < NSTATE) {                                                                \
    for (int j = 0; j < 18; ++j) { G[j].x = (float)A2[L * 18 + j]; G[j].y = (float)A[L * 18 + j]; } \
    double pd0 = 0.0, pd1 = 0.0;                                                   \
    for (int j = 0; j < 18; ++j) { pd0 += A[L * 18 + j] * d0v[j]; pd1 += A[L * 18 + j] * d1v[j]; } \
    C0.x = (float)pd0;            C0.y = (float)d0v[L];                            \
    C1.x = (float)(pd1 + d0v[L]); C1.y = (float)d1v[L];                            \
    C2lo = (float)d1v[L];                                                          \
    F0.x = (float)pc3[L]; F0.y = (float)pc2[L];                                    \
    F1.x = (float)pc2[L]; F1.y = (float)pc1[L];                                    \
    cact = (float)cv[L];                                                           \
    pcact = (float)pc1[L];                                                         \
  } else if (L >= 32 && L < 48) {                                                  \
    int m = L - 32;                                                                \
    double f0 = 0.0, f1 = 0.0, ssum = 0.0;                                         \
    for (int j = 0; j < 18; ++j) {                                                 \
      double g = (double)W1[m * 20 + j] * ((double)PS / 1.41);                     \
      G[j].x = (float)g; G[j].y = 0.f;                                             \
      f0 += g * pc1[j];                                                            \
      f1 += g * cv[j];                                                             \
      ssum += (double)W1[m * 20 + j];                                              \
    }                                                                              \
    F0.x = (float)f0; F1.x = (float)f1;                                            \
    CBlo = (float)(((double)b1[m] - ssum * (23.359 / 1.41)) * (double)PS);         \
    CWlo = W1[m * 20 + 18] * PS * (1.0f / 604800.0f);                              \
    CTlo = W1[m * 20 + 19] * PS * (1.0f / 86400.0f);                               \
    w2A = w2[m]; nw2A = -2.0f * w2A;                                               \
  } else if (L >= 48 && L < 64) {                                                  \
    int m = L - 48;                                                                \
    double f0 = 0.0, f1 = 0.0, ub = 0.0, ssum = 0.0, wd0 = 0.0, wd1 = 0.0;         \
    for (int j = 0; j < 18; ++j) {                                                 \
      double g = (double)W1[m * 20 + j] * ((double)PS / 1.41);                     \
      double wp = 0.0;                                                             \
      for (int k = 0; k < 18; ++k)                                                 \
        wp += (double)W1[m * 20 + k] * ((double)PS / 1.41) * A[k * 18 + j];        \
      G[j].x = (float)wp; G[j].y = 0.f;                                            \
      f0 += g * pc2[j];                                                            \
      f1 += g * pc1[j];                                                            \
      ub += g * cv[j];                                                             \
      wd0 += g * d0v[j];                                                           \
      wd1 += g * d1v[j];                                                           \
      ssum += (double)W1[m * 20 + j];                                              \
    }                                                                              \
    F0.x = (float)f0; F1.x = (float)f1; uB = (float)ub;                            \
    C0.x = (float)wd0; C1.x = (float)wd1;                                          \
    CWlo = W1[m * 20 + 18] * PS * (1.0f / 604800.0f);                              \
    CTlo = W1[m * 20 + 19] * PS * (1.0f / 86400.0f);                               \
    CBlo = (float)(((double)b1[m] - ssum * (23.359 / 1.41)) * (double)PS) +        \
           30.0f * CWlo + 30.0f * CTlo;                                            \
    w2B = w2[m]; nw2B = -2.0f * w2B;                                               \
  } else {                                                                         \
    for (int j = 0; j < 18; ++j) { G[j].x = 0.f; G[j].y = 0.f; }                   \
  }

// common per-lane time-base setup from kb.
#define TIME_BASE_SETUP(kbv)                                                       \
  const unsigned ft0u = (30u * (unsigned)(kbv)) % 86400u;                          \
  const unsigned fw0u = (518400u + 30u * (unsigned)(kbv)) % 604800u;               \
  const int pD = (int)((86400u - ft0u + 59u) / 60u);                               \
  const int pW = (int)((604800u - fw0u + 59u) / 60u);                              \
  float CBase = fmaf((float)ft0u, CTlo, fmaf((float)fw0u, CWlo, CBlo));            \
  const float dtw = fmaf(60.0f, CTlo, 60.0f * CWlo);                               \
  const float dayCorr = 86400.0f * CTlo;                                           \
  const float weekCorr = 604800.0f * CWlo;

// ---------------------------------------------------------------------------
// Setup kernel (split path): runs ONCE. Per-lane constants + quasi-static
// vectors (Jacobi, wave-0 only, no barriers — R12/R13-proven).
//   ws[0..3519]  : per-lane constants   ws[3520+L]: v_t[L]   ws[3584+L]: v_r[L]
// ---------------------------------------------------------------------------
__global__ __launch_bounds__(256) void rc_setup(
    const float* __restrict__ WA, const float* __restrict__ WB,
    const float* __restrict__ W1, const float* __restrict__ b1,
    const float* __restrict__ w2, float* __restrict__ wsf) {
  __shared__ double DB[1440];
  __shared__ double vt[18], vr[18];
  const int L = threadIdx.x;
  const float PS = 2.88539008f;  // 2*log2(e)
  SETUP_BODY(DB, WA, WB, W1, b1, w2, 256);

  if (L < 64) {
#pragma unroll
    for (int j = 0; j < 18; ++j) *(v2f*)(wsf + j * 128 + 2 * L) = G[j];
    *(v2f*)(wsf + 2304 + 0 * 128 + 2 * L) = F0;
    *(v2f*)(wsf + 2304 + 1 * 128 + 2 * L) = F1;
    *(v2f*)(wsf + 2304 + 2 * 128 + 2 * L) = C0;
    *(v2f*)(wsf + 2304 + 3 * 128 + 2 * L) = C1;
    float* scp = wsf + 2816;
    scp[0 * 64 + L] = C2lo;  scp[1 * 64 + L] = CWlo;  scp[2 * 64 + L] = CTlo;
    scp[3 * 64 + L] = CBlo;  scp[4 * 64 + L] = cact;  scp[5 * 64 + L] = pcact;
    scp[6 * 64 + L] = uB;    scp[7 * 64 + L] = w2A;   scp[8 * 64 + L] = nw2A;
    scp[9 * 64 + L] = w2B;   scp[10 * 64 + L] = nw2B;

    // ---- quasi-static vectors: wave-0 only, in-wave DS ordering ----
    if (L < 18) { vt[L] = 1000.0 * bt[L]; vr[L] = 1000.0 * br[L]; }
    for (int it = 0; it < 16; ++it) {
      double st = 0.0, sr = 0.0;
      if (L < 18) {
        for (int j = 0; j < 18; ++j) {
          double w = (double)WA[L * 18 + j];
          st += w * vt[j];
          sr += w * vr[j];
        }
        vt[L] = 1000.0 * bt[L] + 0.1 * st;
        vr[L] = 1000.0 * br[L] + 0.1 * sr;
      }
    }
    if (L < 18) {
      wsf[3520 + L] = (float)vt[L];
      wsf[3584 + L] = (float)vr[L];
    }
  }
}

// ---------------------------------------------------------------------------
// Run kernel (split path): R8 geometry, qs-init, BURN=148, STEPPAIR interleave.
// ---------------------------------------------------------------------------
__global__ __launch_bounds__(64, 4) void rc_run(
    const float* __restrict__ ws, const float* __restrict__ b2,
    const float* __restrict__ iv, const float* __restrict__ tout,
    float* __restrict__ out) {
  __shared__ float ldsT[BURN + RSEGLEN + 2];   // 406 floats
  __shared__ __align__(16) float xbuf[96];

  const int L = threadIdx.x;
  const int idx = blockIdx.x;
  const int b = idx & (NBATCH - 1);
  const int s = idx >> 5;

  const int ks = (s == RSEGS - 1) ? (TSTEPS - 1 - RSEGLEN) : s * RSEGLEN;
  const int kb = max(0, ks - BURN);
  const int mBurn = ks - kb;        // 0 or 148
  const int mEnd = (ks + RSEGLEN) - kb;

  // ---- per-lane constants: coalesced loads from workspace ----
  v2f G[18];
#pragma unroll
  for (int j = 0; j < 18; ++j) G[j] = *(const v2f*)(ws + j * 128 + 2 * L);
  v2f F0 = *(const v2f*)(ws + 2304 + 0 * 128 + 2 * L);
  v2f F1 = *(const v2f*)(ws + 2304 + 1 * 128 + 2 * L);
  v2f C0 = *(const v2f*)(ws + 2304 + 2 * 128 + 2 * L);
  v2f C1 = *(const v2f*)(ws + 2304 + 3 * 128 + 2 * L);
  const float* scp = ws + 2816;
  const float C2lo = scp[0 * 64 + L], CWlo = scp[1 * 64 + L];
  const float CTlo = scp[2 * 64 + L], CBlo = scp[3 * 64 + L];
  const float cact = scp[4 * 64 + L], pcact = scp[5 * 64 + L];
  const float uB   = scp[6 * 64 + L];
  const float w2A  = scp[7 * 64 + L], nw2A = scp[8 * 64 + L];
  const float w2B  = scp[9 * 64 + L], nw2B = scp[10 * 64 + L];
  const float nb2 = -1.44269504f * b2[0];

  TIME_BASE_SETUP(kb);

  // ---- stage tout slice ----
  const int cnt = mEnd + 2;   // up to 406
  for (int i = L; i < cnt; i += 64) ldsT[i] = tout[kb + i];
  __syncthreads();

  // ---- state init: s=0 exact iv; s>0 quasi-static estimate ----
  float q = 0.0f;
  if (L < NSTATE) {
    float qiv = iv[b * NSTATE + L];
    if (s == 0) {
      q = qiv;
    } else {
      float x0 = fmaf(ldsT[0], ws[3520 + L], 0.5f * ws[3584 + L]);
      q = (__builtin_fabsf(x0) < 1.0e4f) ? x0 : qiv;  // NaN/Inf/garbage guard
    }
  }
  if (s == 0 && L < NSTATE) out[b * NSTATE + L] = q;

  float a0p = (s == 0) ? 0.0f : 0.5f;
  float a1p = a0p;

  float* ob = out + (size_t)(ks + 1) * (NBATCH * NSTATE) + b * NSTATE;

  const int wIdx = (L < NSTATE) ? L : (32 + L);
  xbuf[wIdx] = q;               // single-wave block: in-order DS makes this safe
  v2f X[9], Y[9];
#pragma unroll
  for (int j = 0; j < 9; ++j) X[j] = *(const v2f*)(xbuf + 2 * j);

  v2f tU, tV;
  tU.x = ldsT[0]; tU.y = ldsT[1];

  const int nburn = mBurn >> 1;              // 0 or 74 pairs (even)
  const int ntot = mEnd >> 1;                // nburn + 128 pairs (even)
  int p = 0;
  for (; p < nburn; p += 2) {
    STEPPAIR(X, Y, tU, tV, p, false);
  }
  for (; p < ntot; p += 2) {                 // 64 store pair-iterations
    STEPPAIR(X, Y, tU, tV, p, true);
  }
}

// ---------------------------------------------------------------------------
// Fused fallback: single-stream R8 form with iv-init, FBURN=176.
// Used only when workspace is unusable.
// ---------------------------------------------------------------------------
__global__ __launch_bounds__(64, 2) void rc_fused(
    const float* __restrict__ WA, const float* __restrict__ WB,
    const float* __restrict__ W1, const float* __restrict__ b1,
    const float* __restrict__ w2, const float* __restrict__ b2,
    const float* __restrict__ iv, const float* __restrict__ tout,
    float* __restrict__ out) {
  __shared__ double DB[1440];
  __shared__ __align__(16) float xbuf[96];

  const int L = threadIdx.x;
  const int idx = blockIdx.x;
  const int b = idx & (NBATCH - 1);
  const int s = idx >> 5;
  const float PS = 2.88539008f;  // 2*log2(e)

  const int ks = (s == FSEGS - 1) ? (TSTEPS - 1 - FSEGLEN) : s * FSEGLEN;
  const int kb = max(0, ks - FBURN);
  const int mBurn = ks - kb;
  const int mEnd = (ks + FSEGLEN) - kb;

  SETUP_BODY(DB, WA, WB, W1, b1, w2, 64);
  const float b2v = b2[0];
  const float nb2 = -1.44269504f * b2v;
  TIME_BASE_SETUP(kb);
  __syncthreads();

  float* ldsT = (float*)DB;
  const int cnt = mEnd + 2;
  for (int i = L; i < cnt; i += 64) ldsT[i] = tout[kb + i];
  __syncthreads();

  float q = (L < NSTATE) ? iv[b * NSTATE + L] : 0.0f;
  if (s == 0 && L < NSTATE) out[b * NSTATE + L] = q;

  float a0p = 0.0f, a1p = 0.0f;

  float* ob = out + (size_t)(ks + 1) * (NBATCH * NSTATE) + b * NSTATE;

  const int wIdx = (L < NSTATE) ? L : (32 + L);
  xbuf[wIdx] = q;
  v2f X[9], Y[9];
#pragma unroll
  for (int j = 0; j < 9; ++j) X[j] = *(const v2f*)(xbuf + 2 * j);

  v2f tU, tV;
  tU.x = ldsT[0]; tU.y = ldsT[1];

  const int nburn = mBurn >> 1;
  const int ntot = mEnd >> 1;
  int p = 0;
  for (; p < nburn; p += 2) {
    STEPP(X, Y, tU, tV, p, false);     TWRAP(p);
    STEPP(Y, X, tV, tU, p + 1, false); TWRAP(p + 1);
  }
  for (; p < ntot; p += 2) {
    STEPP(X, Y, tU, tV, p, true);      TWRAP(p);
    STEPP(Y, X, tV, tU, p + 1, true);  TWRAP(p + 1);
  }
}

extern "C" void kernel_launch(void* const* d_in, const int* in_sizes, int n_in,
                              void* d_out, int out_size, void* d_ws, size_t ws_size,
                              hipStream_t stream) {
  // inputs: 0=t_eval 1=iv 2=W_A 3=W_B 4=W1 5=b1 6=w2 7=b2 8=Tout_table
  const float* iv = (const float*)d_in[1];
  const float* WA = (const float*)d_in[2];
  const float* WB = (const float*)d_in[3];
  const float* W1 = (const float*)d_in[4];
  const float* b1 = (const float*)d_in[5];
  const float* w2 = (const float*)d_in[6];
  const float* b2 = (const float*)d_in[7];
  const float* tout = (const float*)d_in[8];
  float* out = (float*)d_out;

  if (d_ws != nullptr && ws_size >= 14464) {
    float* wsf = (float*)d_ws;
    rc_setup<<<1, 256, 0, stream>>>(WA, WB, W1, b1, w2, wsf);
    rc_run<<<NBATCH * RSEGS, 64, 0, stream>>>(wsf, b2, iv, tout, out);
  } else {
    rc_fused<<<NBATCH * FSEGS, 64, 0, stream>>>(WA, WB, W1, b1, w2, b2, iv, tout, out);
  }
}